// Round 7
// baseline (473.536 us; speedup 1.0000x reference)
//
#include <hip/hip_runtime.h>
#include <stdint.h>

#define S 2048
#define HID 3584
#define NH 16
#define NKV 8
#define DH 256
#define WINDOW 1024
#define SCALE 0.0625f
#define CAP 50.0f

typedef short s16x8 __attribute__((ext_vector_type(8)));
typedef float f32x4 __attribute__((ext_vector_type(4)));

__device__ __forceinline__ short f2bf(float f) {
  union { float f; uint32_t u; } c; c.f = f;
  uint32_t u = c.u;
  uint32_t r = (u + 0x7FFFu + ((u >> 16) & 1u)) >> 16;
  return (short)r;
}
__device__ __forceinline__ float bf2f(short s) {
  union { uint32_t u; float f; } c;
  c.u = ((uint32_t)(uint16_t)s) << 16;
  return c.f;
}
__device__ __forceinline__ void gll16(const void* g, void* l) {
  __builtin_amdgcn_global_load_lds((const __attribute__((address_space(1))) void*)g,
                                   (__attribute__((address_space(3))) void*)l, 16, 0, 0);
}
#define BAR() asm volatile("s_barrier" ::: "memory")
#define VW6() asm volatile("s_waitcnt vmcnt(6)" ::: "memory")

// ---------------- RoPE table ----------------
__global__ void rope_table_kernel(float2* __restrict__ tbl) {
  int idx = blockIdx.x * 256 + threadIdx.x;
  int s = idx >> 7, i = idx & 127;
  float inv = __expf(-(float)i * (9.210340371976184f / 128.0f));
  float fr = (float)s * inv;
  tbl[idx] = make_float2(cosf(fr), sinf(fr));
}

// ---------------- hs fp32 -> bf16 ----------------
__global__ void conv_hs_kernel(const float* __restrict__ src, short* __restrict__ dst) {
  int gid = blockIdx.x * 256 + threadIdx.x;
  float4 a = *(const float4*)&src[(size_t)gid * 8];
  float4 b = *(const float4*)&src[(size_t)gid * 8 + 4];
  s16x8 o;
  o[0] = f2bf(a.x); o[1] = f2bf(a.y); o[2] = f2bf(a.z); o[3] = f2bf(a.w);
  o[4] = f2bf(b.x); o[5] = f2bf(b.y); o[6] = f2bf(b.z); o[7] = f2bf(b.w);
  *(s16x8*)&dst[(size_t)gid * 8] = o;
}

// ---------------- W fp32 [K][N] -> bf16 [N][K] (transpose+convert) --------
__global__ __launch_bounds__(256)
void transpose_kernel(const float* __restrict__ src, short* __restrict__ dst,
                      int K, int N)
{
  __shared__ __align__(16) short t[64][76];
  int ntn = N >> 6;
  int tn = blockIdx.x % ntn, tk = blockIdx.x / ntn;
  int tid = threadIdx.x;
  int c = tid & 63, rg = tid >> 6;
  #pragma unroll
  for (int i = 0; i < 4; ++i) {
    int r0 = i * 16 + rg * 4;
    short tmp[4];
    #pragma unroll
    for (int j = 0; j < 4; ++j)
      tmp[j] = f2bf(src[(size_t)(tk * 64 + r0 + j) * N + tn * 64 + c]);
    *(short4*)&t[c][r0] = *(short4*)tmp;
  }
  __syncthreads();
  #pragma unroll
  for (int it = 0; it < 2; ++it) {
    int flat = it * 256 + tid;
    int n = flat >> 3, kc = flat & 7;
    *(s16x8*)&dst[(size_t)(tn * 64 + n) * K + tk * 64 + kc * 8] = *(s16x8*)&t[n][kc * 8];
  }
}

// ====== m201-style 8-phase 256xBN GEMM core, BK=64, 512 thr ================
template<int BN, int KS>
__device__ __forceinline__ void gemm_ph(const short* __restrict__ srcA,
                                        const short* __restrict__ srcB,
                                        int tid, int NT,
                                        f32x4 (&acc)[8][BN / 64])
{
  constexpr int NFP = BN / 128;          // n-frags per phase: 2 or 1
  constexpr int BTILE = BN * 64;
  __shared__ __align__(16) short Asb[2 * 16384];
  __shared__ __align__(16) short Bsb[2 * BTILE];
  const int wv = tid >> 6, lane = tid & 63;
  const int lr = lane & 15, lk = lane >> 4;
  const int wm_id = wv >> 2, wn_id = wv & 3;
  const int r7 = lr & 7;
  const int abase = (wm_id * 128 + lr) * 64 + ((lk ^ r7) * 8);
  const int bbase = (wn_id * (BN / 4) + lr) * 64 + ((lk ^ r7) * 8);

  s16x8 af[4][2];            // current m-half frags
  s16x8 bfr[2][NFP][2];      // both n-half frags

  auto stA = [&](int ts, int r, int b) {
    gll16(srcA + (size_t)ts * 64 + (size_t)(r * 64) * KS,
          Asb + b * 16384 + r * 4096 + wv * 512);
  };
  auto stB = [&](int ts, int q, int b) {
    gll16(srcB + (size_t)ts * 64 + (size_t)(q * 64) * KS,
          Bsb + b * BTILE + q * 4096 + wv * 512);
  };
  auto LDA = [&](int mh, int b) {
    const short* A = Asb + b * 16384;
    #pragma unroll
    for (int mf = 0; mf < 4; ++mf)
      #pragma unroll
      for (int kh = 0; kh < 2; ++kh)
        af[mf][kh] = *(const s16x8*)&A[(abase + (mh * 64 + mf * 16) * 64) ^ (kh * 32)];
  };
  auto LDB = [&](int nh, int b) {
    const short* B = Bsb + b * BTILE;
    #pragma unroll
    for (int nf = 0; nf < NFP; ++nf)
      #pragma unroll
      for (int kh = 0; kh < 2; ++kh)
        bfr[nh][nf][kh] = *(const s16x8*)&B[(bbase + (nh * NFP + nf) * 16 * 64) ^ (kh * 32)];
  };
  auto MMA = [&](int mh, int nh) {
    asm volatile("s_waitcnt lgkmcnt(0)" ::: "memory");
    __builtin_amdgcn_sched_barrier(0);
    __builtin_amdgcn_s_setprio(1);
    #pragma unroll
    for (int mf = 0; mf < 4; ++mf)
      #pragma unroll
      for (int nf = 0; nf < NFP; ++nf) {
        acc[mh * 4 + mf][nh * NFP + nf] =
          __builtin_amdgcn_mfma_f32_16x16x32_bf16(af[mf][0], bfr[nh][nf][0],
                                                  acc[mh * 4 + mf][nh * NFP + nf], 0, 0, 0);
        acc[mh * 4 + mf][nh * NFP + nf] =
          __builtin_amdgcn_mfma_f32_16x16x32_bf16(af[mf][1], bfr[nh][nf][1],
                                                  acc[mh * 4 + mf][nh * NFP + nf], 0, 0, 0);
      }
    __builtin_amdgcn_s_setprio(0);
  };

  #pragma unroll
  for (int r = 0; r < 4; ++r) stA(0, r, 0);
  #pragma unroll
  for (int q = 0; q < BN / 64; ++q) stB(0, q, 0);
  #pragma unroll
  for (int r = 0; r < 4; ++r) stA(1, r, 1);
  stB(1, 0, 1); stB(1, 1, 1);
  asm volatile("s_waitcnt vmcnt(0)" ::: "memory");
  BAR();

  const int NI = NT / 2;
  for (int i = 0; i < NI; ++i) {
    const int T = 2 * i;
    const int t2 = (T + 2 < NT) ? T + 2 : NT - 2;
    const int t3 = (T + 3 < NT) ? T + 3 : NT - 1;
    LDA(0, 0); LDB(0, 0);
    if constexpr (BN == 256) { stB(T + 1, 2, 1); stB(T + 1, 3, 1); }
    BAR(); MMA(0, 0); BAR();
    LDB(1, 0);
    stA(t2, 0, 0); stA(t2, 2, 0);
    BAR(); MMA(0, 1); BAR();
    LDA(1, 0);
    stB(t2, 0, 0); stB(t2, 1, 0);
    BAR(); MMA(1, 0); BAR();
    stA(t2, 1, 0); stA(t2, 3, 0);
    VW6();
    BAR(); MMA(1, 1); BAR();
    LDA(0, 1); LDB(0, 1);
    if constexpr (BN == 256) { stB(t2, 2, 0); stB(t2, 3, 0); }
    BAR(); MMA(0, 0); BAR();
    LDB(1, 1);
    stA(t3, 0, 1); stA(t3, 2, 1);
    BAR(); MMA(0, 1); BAR();
    LDA(1, 1);
    stB(t3, 0, 1); stB(t3, 1, 1);
    BAR(); MMA(1, 0); BAR();
    stA(t3, 1, 1); stA(t3, 3, 1);
    VW6();
    BAR(); MMA(1, 1); BAR();
  }
  asm volatile("s_waitcnt vmcnt(0)" ::: "memory");
}

// ---------------- Fused QKV GEMM (256^2) ----------------
__global__ __launch_bounds__(512, 2)
void qkv_gemm8_kernel(const short* __restrict__ hsb, const short* __restrict__ Wt,
                      short* __restrict__ qb, short* __restrict__ kbuf,
                      short* __restrict__ vtb)
{
  int bid = blockIdx.x;
  int swz = (bid & 7) * 32 + (bid >> 3);
  int bm = swz >> 5, bn = swz & 31;
  int m0 = bm * 256, n0 = bn * 256;
  int tid = threadIdx.x;
  int row8 = tid >> 3;
  int colsw = ((tid & 7) ^ (row8 & 7)) * 8;
  const short* srcA = hsb + (size_t)(m0 + row8) * HID + colsw;
  const short* srcB = Wt + (size_t)(n0 + row8) * HID + colsw;
  f32x4 acc[8][4] = {};
  gemm_ph<256, HID>(srcA, srcB, tid, HID / 64, acc);

  int wv = tid >> 6, lane = tid & 63;
  int lr = lane & 15, lk = lane >> 4;
  int wm = (wv >> 2) * 128, wn = (wv & 3) * 64;
  int region = (n0 < 4096) ? 0 : ((n0 < 6144) ? 1 : 2);
  #pragma unroll
  for (int m = 0; m < 8; ++m) {
    int srow_b = m0 + wm + m * 16 + lk * 4;
    #pragma unroll
    for (int n = 0; n < 4; ++n) {
      int ncol = n0 + wn + n * 16 + lr;
      #pragma unroll
      for (int r = 0; r < 4; ++r) {
        int srow = srow_b + r;
        short bv = f2bf(acc[m][n][r]);
        if (region == 0) {
          int h = ncol >> 8, d = ncol & 255;
          qb[((size_t)h * S + srow) * DH + d] = bv;
        } else if (region == 1) {
          int c = ncol - 4096; int kv = c >> 8, d = c & 255;
          kbuf[((size_t)kv * S + srow) * DH + d] = bv;
        } else {
          int c = ncol - 6144; int kv = c >> 8, d = c & 255;
          vtb[((size_t)kv * DH + d) * S + srow] = bv;
        }
      }
    }
  }
}

// ---------------- Output GEMM (256x128) ----------------
__global__ __launch_bounds__(512, 2)
void out_gemm8_kernel(const short* __restrict__ attnb, const short* __restrict__ WtO,
                      float* __restrict__ out)
{
  int bid = blockIdx.x;
  int swz = (bid & 7) * 28 + (bid >> 3);
  int bm = swz / 28, bn = swz % 28;
  int m0 = bm * 256, n0 = bn * 128;
  int tid = threadIdx.x;
  int row8 = tid >> 3;
  int colsw = ((tid & 7) ^ (row8 & 7)) * 8;
  const short* srcA = attnb + (size_t)(m0 + row8) * 4096 + colsw;
  const short* srcB = WtO + (size_t)(n0 + row8) * 4096 + colsw;
  f32x4 acc[8][2] = {};
  gemm_ph<128, 4096>(srcA, srcB, tid, 4096 / 64, acc);

  int wv = tid >> 6, lane = tid & 63;
  int lr = lane & 15, lk = lane >> 4;
  int wm = (wv >> 2) * 128, wn = (wv & 3) * 32;
  #pragma unroll
  for (int m = 0; m < 8; ++m) {
    int srow_b = m0 + wm + m * 16 + lk * 4;
    #pragma unroll
    for (int n = 0; n < 2; ++n) {
      int ncol = n0 + wn + n * 16 + lr;
      #pragma unroll
      for (int r = 0; r < 4; ++r)
        out[(size_t)(srow_b + r) * HID + ncol] = acc[m][n][r];
    }
  }
}

// ---------------- RoPE (NeoX, in place on q and k) ----------------
__global__ void rope_kernel(short* __restrict__ qb, short* __restrict__ kbuf,
                            const float2* __restrict__ tbl)
{
  int gid = blockIdx.x * 256 + threadIdx.x;
  int row = gid >> 4, ch = gid & 15;
  short* base = (row < NH * S) ? (qb + (size_t)row * DH)
                               : (kbuf + (size_t)(row - NH * S) * DH);
  int s = row & (S - 1);
  int i0 = ch * 8;
  s16x8 x1 = *(s16x8*)(base + i0);
  s16x8 x2 = *(s16x8*)(base + 128 + i0);
  s16x8 y1, y2;
  #pragma unroll
  for (int j = 0; j < 8; ++j) {
    float2 cs = tbl[s * 128 + i0 + j];
    float a = bf2f(x1[j]), b = bf2f(x2[j]);
    y1[j] = f2bf(a * cs.x - b * cs.y);
    y2[j] = f2bf(b * cs.x + a * cs.y);
  }
  *(s16x8*)(base + i0) = y1;
  *(s16x8*)(base + 128 + i0) = y2;
}

// ---------------- Attention v3 ----------------
// 4 waves x 16 q-rows, KVBLK=64. K double-buffered in LDS via global_load_lds
// (pre-swizzled source, linear dest), stage(t+1) hidden under compute(t).
// V prefetched to registers in 4 staggered chunks (vtb is [d][s]).
// Fixed-shift softmax (scores tanh-capped to +-CAP => exp(s-CAP)<=1): no
// online max, no rescale; l reduced across lanes once at epilogue.
__global__ __launch_bounds__(256)
void attn_kernel(const short* __restrict__ qb, const short* __restrict__ kbuf,
                 const short* __restrict__ vtb, short* __restrict__ attnb)
{
  __shared__ __align__(16) short Klds[2][64][256];  // swizzled content, 64 KB
  __shared__ __align__(16) short Plds[4][16][72];   // per-wave P, 9 KB
  int bid = blockIdx.x;
  int qt = bid >> 4, h = bid & 15;     // qt-major for pairing balance
  int kv = h >> 1;
  int q0 = qt * 64;
  int tid = threadIdx.x, w = tid >> 6, lane = tid & 63;
  int lr = lane & 15, lk = lane >> 4;
  int qrow_base = q0 + w * 16;
  s16x8 qf[8];
  const short* qrow = qb + ((size_t)h * S + (qrow_base + lr)) * DH;
  #pragma unroll
  for (int kb = 0; kb < 8; ++kb)
    qf[kb] = *(const s16x8*)(qrow + kb * 32 + lk * 8);
  f32x4 acc_o[16] = {};
  float l_r[4] = {0.0f, 0.0f, 0.0f, 0.0f};
  int tlo = (q0 >= WINDOW - 1) ? ((q0 - (WINDOW - 1)) >> 6) : 0;
  int thi = q0 >> 6;
  const short* kbase = kbuf + (size_t)kv * S * DH;
  const short* vbase = vtb + (size_t)kv * DH * S;

  auto stageK = [&](int t, int b) {
    int k0 = t * 64;
    #pragma unroll
    for (int it = 0; it < 8; ++it) {
      int flat = it * 256 + tid;
      int r = flat >> 5, cg = flat & 31;
      int scg = cg ^ (r & 7);                       // pre-swizzled source col
      gll16(kbase + (size_t)(k0 + r) * DH + scg * 8,
            (short*)Klds + b * 16384 + it * 2048 + w * 512);
    }
  };

  stageK(tlo, 0);
  __syncthreads();

  for (int t = tlo; t <= thi; ++t) {
    int k0 = t * 64;
    int cb = (t - tlo) & 1;
    if (t < thi) stageK(t + 1, cb ^ 1);             // hidden under compute
    // QK^T (swizzled conflict-free reads)
    f32x4 sc4[4] = {};
    __builtin_amdgcn_s_setprio(1);
    #pragma unroll
    for (int kb = 0; kb < 8; ++kb)
      #pragma unroll
      for (int ni = 0; ni < 4; ++ni) {
        int row = ni * 16 + lr;
        s16x8 b = *(const s16x8*)&Klds[cb][row][(((kb << 2) | lk) ^ (row & 7)) * 8];
        sc4[ni] = __builtin_amdgcn_mfma_f32_16x16x32_bf16(qf[kb], b, sc4[ni], 0, 0, 0);
      }
    __builtin_amdgcn_s_setprio(0);
    // V prefetch chunks 0,1 (issued before softmax VALU -> latency hidden)
    const short* vcol = vbase + k0 + lk * 8;
    s16x8 va[8], vb[8];
    #pragma unroll
    for (int j = 0; j < 4; ++j) {
      const short* vr = vcol + (size_t)(j * 16 + lr) * S;
      va[2 * j] = *(const s16x8*)vr; va[2 * j + 1] = *(const s16x8*)(vr + 32);
    }
    #pragma unroll
    for (int j = 0; j < 4; ++j) {
      const short* vr = vcol + (size_t)((j + 4) * 16 + lr) * S;
      vb[2 * j] = *(const s16x8*)vr; vb[2 * j + 1] = *(const s16x8*)(vr + 32);
    }
    // softcap + mask + p = exp(capped - CAP)
    bool interior = (k0 + 63 <= qrow_base) && (qrow_base + 15 - k0 < WINDOW);
    #pragma unroll
    for (int ni = 0; ni < 4; ++ni)
      #pragma unroll
      for (int r = 0; r < 4; ++r) {
        float raw = sc4[ni][r];
        float u = fabsf(raw) * (2.0f * SCALE / CAP);
        float e = __expf(-u);                        // in (0,1]
        float th = (1.0f - e) / (1.0f + e);          // |tanh|
        float z = CAP * copysignf(th, raw) - CAP;    // in [-2CAP, 0]
        if (!interior) {
          int qg = qrow_base + lk * 4 + r;
          int kg = k0 + ni * 16 + lr;
          bool valid = (kg <= qg) && (qg - kg < WINDOW);
          z = valid ? z : -1e30f;
        }
        float p = __expf(z);
        sc4[ni][r] = p;
        l_r[r] += p;
      }
    // P -> per-wave LDS, read back as A-frags (no barrier: same wave)
    #pragma unroll
    for (int ni = 0; ni < 4; ++ni)
      #pragma unroll
      for (int r = 0; r < 4; ++r)
        Plds[w][lk * 4 + r][ni * 16 + lr] = f2bf(sc4[ni][r]);
    s16x8 pa0 = *(const s16x8*)&Plds[w][lr][lk * 8];
    s16x8 pa1 = *(const s16x8*)&Plds[w][lr][32 + lk * 8];
    // PV quarters with staggered V reloads
    __builtin_amdgcn_s_setprio(1);
    #pragma unroll
    for (int j = 0; j < 4; ++j) {
      acc_o[j] = __builtin_amdgcn_mfma_f32_16x16x32_bf16(pa0, va[2 * j], acc_o[j], 0, 0, 0);
      acc_o[j] = __builtin_amdgcn_mfma_f32_16x16x32_bf16(pa1, va[2 * j + 1], acc_o[j], 0, 0, 0);
    }
    __builtin_amdgcn_s_setprio(0);
    #pragma unroll
    for (int j = 0; j < 4; ++j) {                    // reload va <- df 8..11
      const short* vr = vcol + (size_t)((j + 8) * 16 + lr) * S;
      va[2 * j] = *(const s16x8*)vr; va[2 * j + 1] = *(const s16x8*)(vr + 32);
    }
    __builtin_amdgcn_s_setprio(1);
    #pragma unroll
    for (int j = 0; j < 4; ++j) {
      acc_o[4 + j] = __builtin_amdgcn_mfma_f32_16x16x32_bf16(pa0, vb[2 * j], acc_o[4 + j], 0, 0, 0);
      acc_o[4 + j] = __builtin_amdgcn_mfma_f32_16x16x32_bf16(pa1, vb[2 * j + 1], acc_o[4 + j], 0, 0, 0);
    }
    __builtin_amdgcn_s_setprio(0);
    #pragma unroll
    for (int j = 0; j < 4; ++j) {                    // reload vb <- df 12..15
      const short* vr = vcol + (size_t)((j + 12) * 16 + lr) * S;
      vb[2 * j] = *(const s16x8*)vr; vb[2 * j + 1] = *(const s16x8*)(vr + 32);
    }
    __builtin_amdgcn_s_setprio(1);
    #pragma unroll
    for (int j = 0; j < 4; ++j) {
      acc_o[8 + j] = __builtin_amdgcn_mfma_f32_16x16x32_bf16(pa0, va[2 * j], acc_o[8 + j], 0, 0, 0);
      acc_o[8 + j] = __builtin_amdgcn_mfma_f32_16x16x32_bf16(pa1, va[2 * j + 1], acc_o[8 + j], 0, 0, 0);
    }
    #pragma unroll
    for (int j = 0; j < 4; ++j) {
      acc_o[12 + j] = __builtin_amdgcn_mfma_f32_16x16x32_bf16(pa0, vb[2 * j], acc_o[12 + j], 0, 0, 0);
      acc_o[12 + j] = __builtin_amdgcn_mfma_f32_16x16x32_bf16(pa1, vb[2 * j + 1], acc_o[12 + j], 0, 0, 0);
    }
    __builtin_amdgcn_s_setprio(0);
    __syncthreads();   // drains vmcnt (stage K(t+1) complete) + buffer handoff
  }
  // epilogue: reduce l across the 16 lr lanes, then write
  #pragma unroll
  for (int r = 0; r < 4; ++r) {
    float lsum = l_r[r];
    #pragma unroll
    for (int off = 1; off < 16; off <<= 1)
      lsum += __shfl_xor(lsum, off, 64);
    float inv = 1.0f / lsum;
    int srow = qrow_base + lk * 4 + r;
    #pragma unroll
    for (int df = 0; df < 16; ++df)
      attnb[(size_t)srow * (NH * DH) + h * DH + df * 16 + lr] = f2bf(acc_o[df][r] * inv);
  }
}

extern "C" void kernel_launch(void* const* d_in, const int* in_sizes, int n_in,
                              void* d_out, int out_size, void* d_ws, size_t ws_size,
                              hipStream_t stream) {
  const float* hs = (const float*)d_in[0];
  const float* Wq = (const float*)d_in[2];
  const float* Wk = (const float*)d_in[3];
  const float* Wv = (const float*)d_in[4];
  const float* Wo = (const float*)d_in[5];
  float* out = (float*)d_out;
  char* ws = (char*)d_ws;
  size_t off = 0;
  float2* tbl  = (float2*)(ws + off); off += 2097152;
  short* qb    = (short*)(ws + off);  off += 16777216;           // q  [H][S][D]
  short* kbuf  = (short*)(ws + off);  off += 8388608;            // k  [KV][S][D]
  short* vtb   = (short*)(ws + off);  off += 8388608;            // vT [KV][D][S]
  short* attnb = (short*)(ws + off);  off += 16777216;           // attn [S][4096]
  short* hsb   = (short*)(ws + off);  off += 14680064;           // hs bf16
  short* Wt    = (short*)(ws + off);  off += 58720256;           // [8192][3584]
  short* WtO   = (short*)(ws + off);  off += 29360128;           // [3584][4096]

  hipLaunchKernelGGL(rope_table_kernel, dim3(1024), dim3(256), 0, stream, tbl);
  hipLaunchKernelGGL(conv_hs_kernel, dim3(3584), dim3(256), 0, stream, hs, hsb);
  hipLaunchKernelGGL(transpose_kernel, dim3(64 * 56), dim3(256), 0, stream,
                     Wq, Wt, HID, 4096);
  hipLaunchKernelGGL(transpose_kernel, dim3(32 * 56), dim3(256), 0, stream,
                     Wk, Wt + (size_t)4096 * HID, HID, 2048);
  hipLaunchKernelGGL(transpose_kernel, dim3(32 * 56), dim3(256), 0, stream,
                     Wv, Wt + (size_t)6144 * HID, HID, 2048);
  hipLaunchKernelGGL(transpose_kernel, dim3(56 * 64), dim3(256), 0, stream,
                     Wo, WtO, 4096, HID);
  hipLaunchKernelGGL(qkv_gemm8_kernel, dim3(256), dim3(512), 0, stream,
                     hsb, Wt, qb, kbuf, vtb);
  hipLaunchKernelGGL(rope_kernel, dim3(3072), dim3(256), 0, stream, qb, kbuf, tbl);
  hipLaunchKernelGGL(attn_kernel, dim3(512), dim3(256), 0, stream,
                     qb, kbuf, vtb, attnb);
  hipLaunchKernelGGL(out_gemm8_kernel, dim3(224), dim3(512), 0, stream,
                     attnb, WtO, out);
}

// Round 8
// 408.626 us; speedup vs baseline: 1.1588x; 1.1588x over previous
//
#include <hip/hip_runtime.h>
#include <stdint.h>

#define S 2048
#define HID 3584
#define NH 16
#define NKV 8
#define DH 256
#define WINDOW 1024
#define SCALE 0.0625f
#define CAP 50.0f

typedef short s16x8 __attribute__((ext_vector_type(8)));
typedef float f32x4 __attribute__((ext_vector_type(4)));

__device__ __forceinline__ short f2bf(float f) {
  union { float f; uint32_t u; } c; c.f = f;
  uint32_t u = c.u;
  uint32_t r = (u + 0x7FFFu + ((u >> 16) & 1u)) >> 16;
  return (short)r;
}
__device__ __forceinline__ float bf2f(short s) {
  union { uint32_t u; float f; } c;
  c.u = ((uint32_t)(uint16_t)s) << 16;
  return c.f;
}
__device__ __forceinline__ void gll16(const void* g, void* l) {
  __builtin_amdgcn_global_load_lds((const __attribute__((address_space(1))) void*)g,
                                   (__attribute__((address_space(3))) void*)l, 16, 0, 0);
}
#define BAR() asm volatile("s_barrier" ::: "memory")
#define VW6() asm volatile("s_waitcnt vmcnt(6)" ::: "memory")

// ---------------- RoPE table ----------------
__global__ void rope_table_kernel(float2* __restrict__ tbl) {
  int idx = blockIdx.x * 256 + threadIdx.x;
  int s = idx >> 7, i = idx & 127;
  float inv = __expf(-(float)i * (9.210340371976184f / 128.0f));
  float fr = (float)s * inv;
  tbl[idx] = make_float2(cosf(fr), sinf(fr));
}

// ---------------- hs fp32 -> bf16 ----------------
__global__ void conv_hs_kernel(const float* __restrict__ src, short* __restrict__ dst) {
  int gid = blockIdx.x * 256 + threadIdx.x;
  float4 a = *(const float4*)&src[(size_t)gid * 8];
  float4 b = *(const float4*)&src[(size_t)gid * 8 + 4];
  s16x8 o;
  o[0] = f2bf(a.x); o[1] = f2bf(a.y); o[2] = f2bf(a.z); o[3] = f2bf(a.w);
  o[4] = f2bf(b.x); o[5] = f2bf(b.y); o[6] = f2bf(b.z); o[7] = f2bf(b.w);
  *(s16x8*)&dst[(size_t)gid * 8] = o;
}

// ---------------- W fp32 [K][N] -> bf16 [N][K] (transpose+convert) --------
__global__ __launch_bounds__(256)
void transpose_kernel(const float* __restrict__ src, short* __restrict__ dst,
                      int K, int N)
{
  __shared__ __align__(16) short t[64][76];
  int ntn = N >> 6;
  int tn = blockIdx.x % ntn, tk = blockIdx.x / ntn;
  int tid = threadIdx.x;
  int c = tid & 63, rg = tid >> 6;
  #pragma unroll
  for (int i = 0; i < 4; ++i) {
    int r0 = i * 16 + rg * 4;
    short tmp[4];
    #pragma unroll
    for (int j = 0; j < 4; ++j)
      tmp[j] = f2bf(src[(size_t)(tk * 64 + r0 + j) * N + tn * 64 + c]);
    *(short4*)&t[c][r0] = *(short4*)tmp;
  }
  __syncthreads();
  #pragma unroll
  for (int it = 0; it < 2; ++it) {
    int flat = it * 256 + tid;
    int n = flat >> 3, kc = flat & 7;
    *(s16x8*)&dst[(size_t)(tn * 64 + n) * K + tk * 64 + kc * 8] = *(s16x8*)&t[n][kc * 8];
  }
}

// ====== m201-style 8-phase 256xBN GEMM core, BK=64, 512 thr ================
template<int BN, int KS>
__device__ __forceinline__ void gemm_ph(const short* __restrict__ srcA,
                                        const short* __restrict__ srcB,
                                        int tid, int NT,
                                        f32x4 (&acc)[8][BN / 64])
{
  constexpr int NFP = BN / 128;          // n-frags per phase: 2 or 1
  constexpr int BTILE = BN * 64;
  __shared__ __align__(16) short Asb[2 * 16384];
  __shared__ __align__(16) short Bsb[2 * BTILE];
  const int wv = tid >> 6, lane = tid & 63;
  const int lr = lane & 15, lk = lane >> 4;
  const int wm_id = wv >> 2, wn_id = wv & 3;
  const int r7 = lr & 7;
  const int abase = (wm_id * 128 + lr) * 64 + ((lk ^ r7) * 8);
  const int bbase = (wn_id * (BN / 4) + lr) * 64 + ((lk ^ r7) * 8);

  s16x8 af[4][2];            // current m-half frags
  s16x8 bfr[2][NFP][2];      // both n-half frags

  auto stA = [&](int ts, int r, int b) {
    gll16(srcA + (size_t)ts * 64 + (size_t)(r * 64) * KS,
          Asb + b * 16384 + r * 4096 + wv * 512);
  };
  auto stB = [&](int ts, int q, int b) {
    gll16(srcB + (size_t)ts * 64 + (size_t)(q * 64) * KS,
          Bsb + b * BTILE + q * 4096 + wv * 512);
  };
  auto LDA = [&](int mh, int b) {
    const short* A = Asb + b * 16384;
    #pragma unroll
    for (int mf = 0; mf < 4; ++mf)
      #pragma unroll
      for (int kh = 0; kh < 2; ++kh)
        af[mf][kh] = *(const s16x8*)&A[(abase + (mh * 64 + mf * 16) * 64) ^ (kh * 32)];
  };
  auto LDB = [&](int nh, int b) {
    const short* B = Bsb + b * BTILE;
    #pragma unroll
    for (int nf = 0; nf < NFP; ++nf)
      #pragma unroll
      for (int kh = 0; kh < 2; ++kh)
        bfr[nh][nf][kh] = *(const s16x8*)&B[(bbase + (nh * NFP + nf) * 16 * 64) ^ (kh * 32)];
  };
  auto MMA = [&](int mh, int nh) {
    asm volatile("s_waitcnt lgkmcnt(0)" ::: "memory");
    __builtin_amdgcn_sched_barrier(0);
    __builtin_amdgcn_s_setprio(1);
    #pragma unroll
    for (int mf = 0; mf < 4; ++mf)
      #pragma unroll
      for (int nf = 0; nf < NFP; ++nf) {
        acc[mh * 4 + mf][nh * NFP + nf] =
          __builtin_amdgcn_mfma_f32_16x16x32_bf16(af[mf][0], bfr[nh][nf][0],
                                                  acc[mh * 4 + mf][nh * NFP + nf], 0, 0, 0);
        acc[mh * 4 + mf][nh * NFP + nf] =
          __builtin_amdgcn_mfma_f32_16x16x32_bf16(af[mf][1], bfr[nh][nf][1],
                                                  acc[mh * 4 + mf][nh * NFP + nf], 0, 0, 0);
      }
    __builtin_amdgcn_s_setprio(0);
  };

  #pragma unroll
  for (int r = 0; r < 4; ++r) stA(0, r, 0);
  #pragma unroll
  for (int q = 0; q < BN / 64; ++q) stB(0, q, 0);
  #pragma unroll
  for (int r = 0; r < 4; ++r) stA(1, r, 1);
  stB(1, 0, 1); stB(1, 1, 1);
  asm volatile("s_waitcnt vmcnt(0)" ::: "memory");
  BAR();

  const int NI = NT / 2;
  for (int i = 0; i < NI; ++i) {
    const int T = 2 * i;
    const int t2 = (T + 2 < NT) ? T + 2 : NT - 2;
    const int t3 = (T + 3 < NT) ? T + 3 : NT - 1;
    LDA(0, 0); LDB(0, 0);
    if constexpr (BN == 256) { stB(T + 1, 2, 1); stB(T + 1, 3, 1); }
    BAR(); MMA(0, 0); BAR();
    LDB(1, 0);
    stA(t2, 0, 0); stA(t2, 2, 0);
    BAR(); MMA(0, 1); BAR();
    LDA(1, 0);
    stB(t2, 0, 0); stB(t2, 1, 0);
    BAR(); MMA(1, 0); BAR();
    stA(t2, 1, 0); stA(t2, 3, 0);
    VW6();
    BAR(); MMA(1, 1); BAR();
    LDA(0, 1); LDB(0, 1);
    if constexpr (BN == 256) { stB(t2, 2, 0); stB(t2, 3, 0); }
    BAR(); MMA(0, 0); BAR();
    LDB(1, 1);
    stA(t3, 0, 1); stA(t3, 2, 1);
    BAR(); MMA(0, 1); BAR();
    LDA(1, 1);
    stB(t3, 0, 1); stB(t3, 1, 1);
    BAR(); MMA(1, 0); BAR();
    stA(t3, 1, 1); stA(t3, 3, 1);
    VW6();
    BAR(); MMA(1, 1); BAR();
  }
  asm volatile("s_waitcnt vmcnt(0)" ::: "memory");
}

// ---------------- Fused QKV GEMM (256^2) ----------------
__global__ __launch_bounds__(512, 2)
void qkv_gemm8_kernel(const short* __restrict__ hsb, const short* __restrict__ Wt,
                      short* __restrict__ qb, short* __restrict__ kbuf,
                      short* __restrict__ vtb)
{
  int bid = blockIdx.x;
  int swz = (bid & 7) * 32 + (bid >> 3);
  int bm = swz >> 5, bn = swz & 31;
  int m0 = bm * 256, n0 = bn * 256;
  int tid = threadIdx.x;
  int row8 = tid >> 3;
  int colsw = ((tid & 7) ^ (row8 & 7)) * 8;
  const short* srcA = hsb + (size_t)(m0 + row8) * HID + colsw;
  const short* srcB = Wt + (size_t)(n0 + row8) * HID + colsw;
  f32x4 acc[8][4] = {};
  gemm_ph<256, HID>(srcA, srcB, tid, HID / 64, acc);

  int wv = tid >> 6, lane = tid & 63;
  int lr = lane & 15, lk = lane >> 4;
  int wm = (wv >> 2) * 128, wn = (wv & 3) * 64;
  int region = (n0 < 4096) ? 0 : ((n0 < 6144) ? 1 : 2);
  #pragma unroll
  for (int m = 0; m < 8; ++m) {
    int srow_b = m0 + wm + m * 16 + lk * 4;
    #pragma unroll
    for (int n = 0; n < 4; ++n) {
      int ncol = n0 + wn + n * 16 + lr;
      #pragma unroll
      for (int r = 0; r < 4; ++r) {
        int srow = srow_b + r;
        short bv = f2bf(acc[m][n][r]);
        if (region == 0) {
          int h = ncol >> 8, d = ncol & 255;
          qb[((size_t)h * S + srow) * DH + d] = bv;
        } else if (region == 1) {
          int c = ncol - 4096; int kv = c >> 8, d = c & 255;
          kbuf[((size_t)kv * S + srow) * DH + d] = bv;
        } else {
          int c = ncol - 6144; int kv = c >> 8, d = c & 255;
          vtb[((size_t)kv * DH + d) * S + srow] = bv;
        }
      }
    }
  }
}

// ---------------- Output GEMM (256x128) ----------------
__global__ __launch_bounds__(512, 2)
void out_gemm8_kernel(const short* __restrict__ attnb, const short* __restrict__ WtO,
                      float* __restrict__ out)
{
  int bid = blockIdx.x;
  int swz = (bid & 7) * 28 + (bid >> 3);
  int bm = swz / 28, bn = swz % 28;
  int m0 = bm * 256, n0 = bn * 128;
  int tid = threadIdx.x;
  int row8 = tid >> 3;
  int colsw = ((tid & 7) ^ (row8 & 7)) * 8;
  const short* srcA = attnb + (size_t)(m0 + row8) * 4096 + colsw;
  const short* srcB = WtO + (size_t)(n0 + row8) * 4096 + colsw;
  f32x4 acc[8][2] = {};
  gemm_ph<128, 4096>(srcA, srcB, tid, 4096 / 64, acc);

  int wv = tid >> 6, lane = tid & 63;
  int lr = lane & 15, lk = lane >> 4;
  int wm = (wv >> 2) * 128, wn = (wv & 3) * 32;
  #pragma unroll
  for (int m = 0; m < 8; ++m) {
    int srow_b = m0 + wm + m * 16 + lk * 4;
    #pragma unroll
    for (int n = 0; n < 2; ++n) {
      int ncol = n0 + wn + n * 16 + lr;
      #pragma unroll
      for (int r = 0; r < 4; ++r)
        out[(size_t)(srow_b + r) * HID + ncol] = acc[m][n][r];
    }
  }
}

// ---------------- RoPE (NeoX, in place on q and k) ----------------
__global__ void rope_kernel(short* __restrict__ qb, short* __restrict__ kbuf,
                            const float2* __restrict__ tbl)
{
  int gid = blockIdx.x * 256 + threadIdx.x;
  int row = gid >> 4, ch = gid & 15;
  short* base = (row < NH * S) ? (qb + (size_t)row * DH)
                               : (kbuf + (size_t)(row - NH * S) * DH);
  int s = row & (S - 1);
  int i0 = ch * 8;
  s16x8 x1 = *(s16x8*)(base + i0);
  s16x8 x2 = *(s16x8*)(base + 128 + i0);
  s16x8 y1, y2;
  #pragma unroll
  for (int j = 0; j < 8; ++j) {
    float2 cs = tbl[s * 128 + i0 + j];
    float a = bf2f(x1[j]), b = bf2f(x2[j]);
    y1[j] = f2bf(a * cs.x - b * cs.y);
    y2[j] = f2bf(b * cs.x + a * cs.y);
  }
  *(s16x8*)(base + i0) = y1;
  *(s16x8*)(base + 128 + i0) = y2;
}

// ---------------- Attention v4 (R5 skeleton + targeted fixes) -------------
// 4 waves x 16 q-rows, KVBLK=64. K+V cooperatively staged into LDS each tile
// (proven R5 structure), with T14 split: next tile's K/V global loads issued
// into REGISTERS right after the compute-entry barrier (latency hidden under
// the full compute phase), regs->LDS at tile top. K LDS XOR-swizzled
// (conflict-free QK reads). Fixed-shift softmax (p = exp(capped-CAP)): no
// online max, no rescale, no per-tile shuffles.
__global__ __launch_bounds__(256)
void attn_kernel(const short* __restrict__ qb, const short* __restrict__ kbuf,
                 const short* __restrict__ vtb, short* __restrict__ attnb)
{
  __shared__ __align__(16) short Klds[64][256];   // swizzled: chunk ^= row&7
  __shared__ __align__(16) short Vlds[256][72];   // [d][k], pad 72
  __shared__ __align__(16) short Plds[4][16][76]; // per-wave P, pad 76
  int bid = blockIdx.x;
  int qt = bid >> 4, h = bid & 15;     // qt-major: better static balance
  int kv = h >> 1;
  int q0 = qt * 64;
  int tid = threadIdx.x, w = tid >> 6, lane = tid & 63;
  int lr = lane & 15, lk = lane >> 4;
  int qrow_base = q0 + w * 16;
  s16x8 qf[8];
  const short* qrow = qb + ((size_t)h * S + (qrow_base + lr)) * DH;
  #pragma unroll
  for (int kb = 0; kb < 8; ++kb)
    qf[kb] = *(const s16x8*)(qrow + kb * 32 + lk * 8);
  f32x4 acc_o[16] = {};
  float l_r[4] = {0.0f, 0.0f, 0.0f, 0.0f};
  int tlo = (q0 >= WINDOW - 1) ? ((q0 - (WINDOW - 1)) >> 6) : 0;
  int thi = q0 >> 6;
  const short* kbase = kbuf + (size_t)kv * S * DH;
  const short* vbase = vtb + (size_t)kv * DH * S;

  s16x8 kpf[8], vpf[8];                 // next-tile staging registers
  auto loadRegs = [&](int t) {
    int k0 = t * 64;
    #pragma unroll
    for (int it = 0; it < 8; ++it) {
      int flat = it * 256 + tid;
      int r = flat >> 5, cg = flat & 31;
      kpf[it] = *(const s16x8*)(kbase + (size_t)(k0 + r) * DH + cg * 8);
    }
    #pragma unroll
    for (int it = 0; it < 8; ++it) {
      int flat = it * 256 + tid;
      int r = flat >> 3, cg = flat & 7;
      vpf[it] = *(const s16x8*)(vbase + (size_t)r * S + k0 + cg * 8);
    }
  };
  auto writeLds = [&]() {
    #pragma unroll
    for (int it = 0; it < 8; ++it) {
      int flat = it * 256 + tid;
      int r = flat >> 5, cg = flat & 31;
      *(s16x8*)&Klds[r][(cg ^ (r & 7)) * 8] = kpf[it];
    }
    #pragma unroll
    for (int it = 0; it < 8; ++it) {
      int flat = it * 256 + tid;
      int r = flat >> 3, cg = flat & 7;
      *(s16x8*)&Vlds[r][cg * 8] = vpf[it];
    }
  };

  loadRegs(tlo);
  for (int t = tlo; t <= thi; ++t) {
    int k0 = t * 64;
    writeLds();                         // auto vmcnt waits; loads long done
    __syncthreads();
    if (t < thi) loadRegs(t + 1);       // in flight under whole compute phase
    // QK^T (swizzled conflict-free reads)
    f32x4 sc4[4] = {};
    __builtin_amdgcn_s_setprio(1);
    #pragma unroll
    for (int kb = 0; kb < 8; ++kb)
      #pragma unroll
      for (int ni = 0; ni < 4; ++ni) {
        int row = ni * 16 + lr;
        s16x8 b = *(const s16x8*)&Klds[row][(((kb << 2) | lk) ^ (row & 7)) * 8];
        sc4[ni] = __builtin_amdgcn_mfma_f32_16x16x32_bf16(qf[kb], b, sc4[ni], 0, 0, 0);
      }
    __builtin_amdgcn_s_setprio(0);
    // softcap (fast tanh) + mask + p = exp(capped - CAP)
    bool interior = (k0 + 63 <= qrow_base) && (qrow_base + 15 - k0 < WINDOW);
    #pragma unroll
    for (int ni = 0; ni < 4; ++ni)
      #pragma unroll
      for (int r = 0; r < 4; ++r) {
        float raw = sc4[ni][r];
        float u = fabsf(raw) * (2.0f * SCALE / CAP);
        float e = __expf(-u);
        float th = (1.0f - e) / (1.0f + e);
        float z = CAP * copysignf(th, raw) - CAP;    // in [-2CAP, 0]
        if (!interior) {
          int qg = qrow_base + lk * 4 + r;
          int kg = k0 + ni * 16 + lr;
          bool valid = (kg <= qg) && (qg - kg < WINDOW);
          z = valid ? z : -1e30f;
        }
        float p = __expf(z);
        sc4[ni][r] = p;
        l_r[r] += p;
      }
    // P -> per-wave LDS, read back as A-frags (same wave: no barrier)
    #pragma unroll
    for (int ni = 0; ni < 4; ++ni)
      #pragma unroll
      for (int r = 0; r < 4; ++r)
        Plds[w][lk * 4 + r][ni * 16 + lr] = f2bf(sc4[ni][r]);
    s16x8 pa0 = *(const s16x8*)&Plds[w][lr][lk * 8];
    s16x8 pa1 = *(const s16x8*)&Plds[w][lr][32 + lk * 8];
    // PV from Vlds
    __builtin_amdgcn_s_setprio(1);
    #pragma unroll
    for (int df = 0; df < 16; ++df) {
      s16x8 b0 = *(const s16x8*)&Vlds[df * 16 + lr][lk * 8];
      s16x8 b1 = *(const s16x8*)&Vlds[df * 16 + lr][32 + lk * 8];
      acc_o[df] = __builtin_amdgcn_mfma_f32_16x16x32_bf16(pa0, b0, acc_o[df], 0, 0, 0);
      acc_o[df] = __builtin_amdgcn_mfma_f32_16x16x32_bf16(pa1, b1, acc_o[df], 0, 0, 0);
    }
    __builtin_amdgcn_s_setprio(0);
    __syncthreads();                    // all reads done before next overwrite
  }
  // epilogue: reduce l across the 16 k-lanes, then write
  #pragma unroll
  for (int r = 0; r < 4; ++r) {
    float lsum = l_r[r];
    #pragma unroll
    for (int off = 1; off < 16; off <<= 1)
      lsum += __shfl_xor(lsum, off, 64);
    float inv = 1.0f / lsum;
    int srow = qrow_base + lk * 4 + r;
    #pragma unroll
    for (int df = 0; df < 16; ++df)
      attnb[(size_t)srow * (NH * DH) + h * DH + df * 16 + lr] = f2bf(acc_o[df][r] * inv);
  }
}

extern "C" void kernel_launch(void* const* d_in, const int* in_sizes, int n_in,
                              void* d_out, int out_size, void* d_ws, size_t ws_size,
                              hipStream_t stream) {
  const float* hs = (const float*)d_in[0];
  const float* Wq = (const float*)d_in[2];
  const float* Wk = (const float*)d_in[3];
  const float* Wv = (const float*)d_in[4];
  const float* Wo = (const float*)d_in[5];
  float* out = (float*)d_out;
  char* ws = (char*)d_ws;
  size_t off = 0;
  float2* tbl  = (float2*)(ws + off); off += 2097152;
  short* qb    = (short*)(ws + off);  off += 16777216;           // q  [H][S][D]
  short* kbuf  = (short*)(ws + off);  off += 8388608;            // k  [KV][S][D]
  short* vtb   = (short*)(ws + off);  off += 8388608;            // vT [KV][D][S]
  short* attnb = (short*)(ws + off);  off += 16777216;           // attn [S][4096]
  short* hsb   = (short*)(ws + off);  off += 14680064;           // hs bf16
  short* Wt    = (short*)(ws + off);  off += 58720256;           // [8192][3584]
  short* WtO   = (short*)(ws + off);  off += 29360128;           // [3584][4096]

  hipLaunchKernelGGL(rope_table_kernel, dim3(1024), dim3(256), 0, stream, tbl);
  hipLaunchKernelGGL(conv_hs_kernel, dim3(3584), dim3(256), 0, stream, hs, hsb);
  hipLaunchKernelGGL(transpose_kernel, dim3(64 * 56), dim3(256), 0, stream,
                     Wq, Wt, HID, 4096);
  hipLaunchKernelGGL(transpose_kernel, dim3(32 * 56), dim3(256), 0, stream,
                     Wk, Wt + (size_t)4096 * HID, HID, 2048);
  hipLaunchKernelGGL(transpose_kernel, dim3(32 * 56), dim3(256), 0, stream,
                     Wv, Wt + (size_t)6144 * HID, HID, 2048);
  hipLaunchKernelGGL(transpose_kernel, dim3(56 * 64), dim3(256), 0, stream,
                     Wo, WtO, 4096, HID);
  hipLaunchKernelGGL(qkv_gemm8_kernel, dim3(256), dim3(512), 0, stream,
                     hsb, Wt, qb, kbuf, vtb);
  hipLaunchKernelGGL(rope_kernel, dim3(3072), dim3(256), 0, stream, qb, kbuf, tbl);
  hipLaunchKernelGGL(attn_kernel, dim3(512), dim3(256), 0, stream,
                     qb, kbuf, vtb, attnb);
  hipLaunchKernelGGL(out_gemm8_kernel, dim3(224), dim3(512), 0, stream,
                     attnb, WtO, out);
}